// Round 4
// baseline (2474.895 us; speedup 1.0000x reference)
//
#include <hip/hip_runtime.h>

#define N_NODES    100000
#define N_EDGES    1600000
#define IN_CH      128
#define HID        64
#define N_LAYERS   4
#define OUT_CH     10
#define NUM_GRAPHS 128
#define BN_EPS     1e-5f

// All tensors fp32 per the reference (jnp.float32); edge_index/batch int32.

// ---------------- utility: zero a float buffer (no hipMemsetAsync) -----------
__global__ void zero_f(float* __restrict__ p, long n) {
    long i = (long)blockIdx.x * blockDim.x + threadIdx.x;
    long st = (long)gridDim.x * blockDim.x;
    for (; i < n; i += st) p[i] = 0.f;
}

// ---------------- scatter-add (segment_sum of gathered features) -------------
__global__ void scatter0(const float* __restrict__ x, const int* __restrict__ src,
                         const int* __restrict__ dst, float* __restrict__ agg) {
    long i = (long)blockIdx.x * 256 + threadIdx.x;
    long st = (long)gridDim.x * 256;
    const long total = (long)N_EDGES * 128;
    for (; i < total; i += st) {
        int e = (int)(i >> 7), c = (int)(i & 127);
        atomicAdd(agg + (long)dst[e] * 128 + c, x[(long)src[e] * 128 + c]);
    }
}

__global__ void scatter64(const float* __restrict__ h, const int* __restrict__ src,
                          const int* __restrict__ dst, float* __restrict__ agg) {
    long i = (long)blockIdx.x * 256 + threadIdx.x;
    long st = (long)gridDim.x * 256;
    const long total = (long)N_EDGES * 64;
    for (; i < total; i += st) {
        int e = (int)(i >> 6), c = (int)(i & 63);
        atomicAdd(agg + (long)dst[e] * 64 + c, h[(long)src[e] * 64 + c]);
    }
}

// ---------------- per-node GIN MLP + JK accumulation (layer 0, K=128) --------
// h_out = relu( relu((x+agg)@W1 + b1) @ W2 + b2 );  jk = h_out @ Wjk_blk
__global__ void mlp0(const float* __restrict__ x, const float* __restrict__ agg,
                     const float* __restrict__ W1, const float* __restrict__ b1,
                     const float* __restrict__ W2, const float* __restrict__ b2,
                     const float* __restrict__ Wjk_blk,
                     float* __restrict__ hout, float* __restrict__ jk) {
    __shared__ float zsh[4][IN_CH];
    __shared__ float tsh[4][64];
    const int wave = threadIdx.x >> 6, lane = threadIdx.x & 63;
    const int n = blockIdx.x * 4 + wave;          // 25000 blocks * 4 == 100000

    const float* aggn = agg + (long)n * IN_CH;
    const float* xn   = x   + (long)n * IN_CH;
    zsh[wave][lane]      = xn[lane]      + aggn[lane];
    zsh[wave][lane + 64] = xn[lane + 64] + aggn[lane + 64];
    __syncthreads();

    float acc = b1[lane];
    for (int k = 0; k < IN_CH; k++) acc += zsh[wave][k] * W1[k * 64 + lane];
    acc = fmaxf(acc, 0.f);
    tsh[wave][lane] = acc;
    __syncthreads();

    float acc2 = b2[lane];
    for (int k = 0; k < 64; k++) acc2 += tsh[wave][k] * W2[k * 64 + lane];
    acc2 = fmaxf(acc2, 0.f);
    hout[(long)n * 64 + lane] = acc2;
    __syncthreads();

    tsh[wave][lane] = acc2;
    __syncthreads();
    float jkv = 0.f;
    for (int k = 0; k < 64; k++) jkv += tsh[wave][k] * Wjk_blk[k * 64 + lane];
    jk[(long)n * 64 + lane] = jkv;
}

// ---------------- per-node GIN MLP + JK accumulation (layers 1..3, K=64) -----
__global__ void mlp64(const float* __restrict__ hin, const float* __restrict__ agg,
                      const float* __restrict__ W1, const float* __restrict__ b1,
                      const float* __restrict__ W2, const float* __restrict__ b2,
                      const float* __restrict__ Wjk_blk,
                      float* __restrict__ hout, float* __restrict__ jk) {
    __shared__ float zsh[4][64];
    __shared__ float tsh[4][64];
    const int wave = threadIdx.x >> 6, lane = threadIdx.x & 63;
    const int n = blockIdx.x * 4 + wave;

    zsh[wave][lane] = hin[(long)n * 64 + lane] + agg[(long)n * 64 + lane];
    __syncthreads();

    float acc = b1[lane];
    for (int k = 0; k < 64; k++) acc += zsh[wave][k] * W1[k * 64 + lane];
    acc = fmaxf(acc, 0.f);
    tsh[wave][lane] = acc;
    __syncthreads();

    float acc2 = b2[lane];
    for (int k = 0; k < 64; k++) acc2 += tsh[wave][k] * W2[k * 64 + lane];
    acc2 = fmaxf(acc2, 0.f);
    hout[(long)n * 64 + lane] = acc2;
    __syncthreads();

    tsh[wave][lane] = acc2;
    __syncthreads();
    float jkv = 0.f;
    for (int k = 0; k < 64; k++) jkv += tsh[wave][k] * Wjk_blk[k * 64 + lane];
    jk[(long)n * 64 + lane] += jkv;
}

// ---------------- global add pool (batch is sorted) --------------------------
__global__ void pool_kernel(const float* __restrict__ jk, const int* __restrict__ batch,
                            const float* __restrict__ bjk, float* __restrict__ pooled) {
    const int NPB = 125;                          // 800 blocks * 125 == 100000
    int s = blockIdx.x * NPB, e = s + NPB;
    int lane = threadIdx.x;                       // 64 threads
    float bj = bjk[lane];
    float acc = 0.f;
    int gcur = batch[s];
    for (int n = s; n < e; n++) {
        int g = batch[n];
        if (g != gcur) {
            atomicAdd(pooled + gcur * 64 + lane, acc);
            acc = 0.f; gcur = g;
        }
        acc += jk[(long)n * 64 + lane] + bj;
    }
    atomicAdd(pooled + gcur * 64 + lane, acc);
}

// ---------------- classifier, split into 3 LDS-free micro-kernels ------------
__global__ void cls_z(const float* __restrict__ pooled, const float* __restrict__ Wc1,
                      const float* __restrict__ bc1, float* __restrict__ z) {
    int g = blockIdx.x, j = threadIdx.x;          // 128 blocks x 64 threads
    float acc = bc1[j];
    for (int k = 0; k < 64; k++) acc += pooled[g * 64 + k] * Wc1[k * 64 + j];
    z[g * 64 + j] = acc;
}

__global__ void cls_bn(const float* __restrict__ z, float* __restrict__ mu,
                       float* __restrict__ rstd) {
    int j = threadIdx.x;                          // 1 block x 64 threads
    float s = 0.f, sq = 0.f;
    for (int g = 0; g < NUM_GRAPHS; g++) {
        float v = z[g * 64 + j];
        s += v; sq += v * v;
    }
    float m = s / NUM_GRAPHS;
    mu[j] = m;
    rstd[j] = rsqrtf(sq / NUM_GRAPHS - m * m + BN_EPS);
}

__global__ void cls_out(const float* __restrict__ z, const float* __restrict__ mu,
                        const float* __restrict__ rstd,
                        const float* __restrict__ gamma, const float* __restrict__ beta,
                        const float* __restrict__ Wc2, const float* __restrict__ bc2,
                        float* __restrict__ out) {
    int i = blockIdx.x * 64 + threadIdx.x;        // 20 blocks x 64 = 1280 exact
    int g = i / OUT_CH, o = i % OUT_CH;
    float acc = bc2[o];
    for (int j = 0; j < 64; j++) {
        float v = (z[g * 64 + j] - mu[j]) * rstd[j] * gamma[j] + beta[j];
        v = fmaxf(v, 0.f);
        acc += v * Wc2[j * OUT_CH + o];
    }
    out[i] = acc;
}

// -----------------------------------------------------------------------------
extern "C" void kernel_launch(void* const* d_in, const int* in_sizes, int n_in,
                              void* d_out, int out_size, void* d_ws, size_t ws_size,
                              hipStream_t stream) {
    const float* x     = (const float*)d_in[0];
    const int*   ei    = (const int*)d_in[1];
    const int*   batch = (const int*)d_in[2];
    const float* W1f   = (const float*)d_in[3];
    const float* b1f   = (const float*)d_in[4];
    const float* W2f   = (const float*)d_in[5];
    const float* b2f   = (const float*)d_in[6];
    const float* W1r   = (const float*)d_in[7];
    const float* b1r   = (const float*)d_in[8];
    const float* W2r   = (const float*)d_in[9];
    const float* b2r   = (const float*)d_in[10];
    const float* Wjk   = (const float*)d_in[11];
    const float* bjk   = (const float*)d_in[12];
    const float* Wc1   = (const float*)d_in[13];
    const float* bc1   = (const float*)d_in[14];
    const float* gamma = (const float*)d_in[15];
    const float* beta  = (const float*)d_in[16];
    const float* Wc2   = (const float*)d_in[17];
    const float* bc2   = (const float*)d_in[18];

    const int* src = ei;
    const int* dst = ei + N_EDGES;

    float* ws     = (float*)d_ws;
    float* agg    = ws;                                   // 12.8M floats
    float* hA     = agg + (long)N_NODES * IN_CH;          // 6.4M floats
    float* hB     = hA + (long)N_NODES * HID;             // 6.4M floats
    float* jk     = hB + (long)N_NODES * HID;             // 6.4M floats
    float* zbuf   = jk + (long)N_NODES * HID;             // 8192 floats
    float* mu     = zbuf + NUM_GRAPHS * HID;              // 64
    float* rstd   = mu + HID;                             // 64
    float* pooled = rstd + HID;                           // 8192 floats

    // ---- layer 0 ----
    zero_f<<<8192, 256, 0, stream>>>(agg, (long)N_NODES * IN_CH);
    zero_f<<<32, 256, 0, stream>>>(pooled, (long)NUM_GRAPHS * HID);
    scatter0<<<32768, 256, 0, stream>>>(x, src, dst, agg);
    mlp0<<<N_NODES / 4, 256, 0, stream>>>(x, agg, W1f, b1f, W2f, b2f, Wjk, hA, jk);

    // ---- layers 1..3 ----
    float* hin = hA; float* hout = hB;
    for (int l = 1; l < N_LAYERS; l++) {
        zero_f<<<8192, 256, 0, stream>>>(agg, (long)N_NODES * HID);
        scatter64<<<32768, 256, 0, stream>>>(hin, src, dst, agg);
        mlp64<<<N_NODES / 4, 256, 0, stream>>>(
            hin, agg,
            W1r + (long)(l - 1) * HID * HID, b1r + (long)(l - 1) * HID,
            W2r + (long)(l - 1) * HID * HID, b2r + (long)(l - 1) * HID,
            Wjk + (long)l * HID * HID, hout, jk);
        float* tmp = hin; hin = hout; hout = tmp;
    }

    // ---- JK bias + global add pool ----
    pool_kernel<<<N_NODES / 125, 64, 0, stream>>>(jk, batch, bjk, pooled);

    // ---- classifier ----
    cls_z<<<NUM_GRAPHS, 64, 0, stream>>>(pooled, Wc1, bc1, zbuf);
    cls_bn<<<1, 64, 0, stream>>>(zbuf, mu, rstd);
    cls_out<<<(NUM_GRAPHS * OUT_CH) / 64, 64, 0, stream>>>(
        zbuf, mu, rstd, gamma, beta, Wc2, bc2, (float*)d_out);
}

// Round 5
// 1312.448 us; speedup vs baseline: 1.8857x; 1.8857x over previous
//
#include <hip/hip_runtime.h>

#define N_NODES    100000
#define N_EDGES    1600000
#define IN_CH      128
#define HID        64
#define N_LAYERS   4
#define OUT_CH     10
#define NUM_GRAPHS 128
#define BN_EPS     1e-5f
#define SCAN_NB    391            // ceil(100000/256)

// ---------------- utility zeroing (no hipMemsetAsync under graph capture) ----
__global__ void zero_i(int* __restrict__ p, int n) {
    int i = blockIdx.x * 256 + threadIdx.x;
    int st = gridDim.x * 256;
    for (; i < n; i += st) p[i] = 0;
}
__global__ void zero_f(float* __restrict__ p, int n) {
    int i = blockIdx.x * 256 + threadIdx.x;
    int st = gridDim.x * 256;
    for (; i < n; i += st) p[i] = 0.f;
}

// ---------------- CSR build: rows = dst, cols = src --------------------------
__global__ void hist(const int* __restrict__ dst, int* __restrict__ cnt) {
    int e = blockIdx.x * 256 + threadIdx.x;       // 6250 * 256 == 1.6M exact
    atomicAdd(&cnt[dst[e]], 1);
}

// per-256-chunk exclusive scan + chunk totals
__global__ void scan_local(const int* __restrict__ cnt, int* __restrict__ row_start,
                           int* __restrict__ bsum) {
    __shared__ int sh[256];
    int t = threadIdx.x, i = blockIdx.x * 256 + t;
    int v = (i < N_NODES) ? cnt[i] : 0;
    sh[t] = v;
    __syncthreads();
    for (int off = 1; off < 256; off <<= 1) {
        int add = (t >= off) ? sh[t - off] : 0;
        __syncthreads();
        sh[t] += add;
        __syncthreads();
    }
    if (i < N_NODES) row_start[i] = sh[t] - v;    // exclusive
    if (t == 255) bsum[blockIdx.x] = sh[255];
}

// serial scan of 391 chunk totals (tiny)
__global__ void scan_bsum(int* __restrict__ bsum) {
    if (threadIdx.x == 0) {
        int acc = 0;
        for (int b = 0; b < SCAN_NB; b++) { int v = bsum[b]; bsum[b] = acc; acc += v; }
    }
}

__global__ void add_off(int* __restrict__ row_start, const int* __restrict__ bsum) {
    int i = blockIdx.x * 256 + threadIdx.x;
    if (i < N_NODES) row_start[i] += bsum[blockIdx.x];
    if (i == 0) row_start[N_NODES] = N_EDGES;
}

__global__ void fill_csr(const int* __restrict__ src, const int* __restrict__ dst,
                         const int* __restrict__ row_start, int* __restrict__ cur,
                         int* __restrict__ col) {
    int e = blockIdx.x * 256 + threadIdx.x;       // 6250 * 256
    int d = dst[e];
    int slot = row_start[d] + atomicAdd(&cur[d], 1);
    col[slot] = src[e];
}

// ---------------- fused gather + GIN MLP + JK (layer 0, K=128) ---------------
// z = x[n] + sum_{s in in(n)} x[s];  h = relu(relu(z@W1+b1)@W2+b2);  jk = h@Wjk0
__global__ void mlp0_fused(const float* __restrict__ x,
                           const int* __restrict__ row_start, const int* __restrict__ col,
                           const float* __restrict__ W1, const float* __restrict__ b1,
                           const float* __restrict__ W2, const float* __restrict__ b2,
                           const float* __restrict__ Wjk_blk,
                           float* __restrict__ hout, float* __restrict__ jk) {
    __shared__ float zsh[4][IN_CH];
    __shared__ float tsh[4][64];
    const int wave = threadIdx.x >> 6, lane = threadIdx.x & 63;
    const int n = blockIdx.x * 4 + wave;          // 25000 * 4 == 100000

    float z0 = x[(long)n * IN_CH + lane];
    float z1 = x[(long)n * IN_CH + 64 + lane];
    int s = row_start[n], e = row_start[n + 1];
    int i = s;
    for (; i + 1 < e; i += 2) {
        int c0 = col[i], c1 = col[i + 1];
        const float* r0 = x + (long)c0 * IN_CH;
        const float* r1 = x + (long)c1 * IN_CH;
        float a0 = r0[lane], a1 = r0[64 + lane];
        float b0 = r1[lane], b1v = r1[64 + lane];
        z0 += a0 + b0; z1 += a1 + b1v;
    }
    if (i < e) {
        const float* r0 = x + (long)col[i] * IN_CH;
        z0 += r0[lane]; z1 += r0[64 + lane];
    }
    zsh[wave][lane] = z0; zsh[wave][64 + lane] = z1;
    __syncthreads();

    float acc = b1[lane];
    for (int k = 0; k < IN_CH; k++) acc += zsh[wave][k] * W1[k * 64 + lane];
    acc = fmaxf(acc, 0.f);
    tsh[wave][lane] = acc;
    __syncthreads();

    float acc2 = b2[lane];
    for (int k = 0; k < 64; k++) acc2 += tsh[wave][k] * W2[k * 64 + lane];
    acc2 = fmaxf(acc2, 0.f);
    hout[(long)n * 64 + lane] = acc2;
    __syncthreads();

    tsh[wave][lane] = acc2;
    __syncthreads();
    float jkv = 0.f;
    for (int k = 0; k < 64; k++) jkv += tsh[wave][k] * Wjk_blk[k * 64 + lane];
    jk[(long)n * 64 + lane] = jkv;
}

// ---------------- fused gather + GIN MLP + JK (layers 1..3, K=64) ------------
__global__ void mlp64_fused(const float* __restrict__ hin,
                            const int* __restrict__ row_start, const int* __restrict__ col,
                            const float* __restrict__ W1, const float* __restrict__ b1,
                            const float* __restrict__ W2, const float* __restrict__ b2,
                            const float* __restrict__ Wjk_blk,
                            float* __restrict__ hout, float* __restrict__ jk) {
    __shared__ float zsh[4][64];
    __shared__ float tsh[4][64];
    const int wave = threadIdx.x >> 6, lane = threadIdx.x & 63;
    const int n = blockIdx.x * 4 + wave;

    float z = hin[(long)n * 64 + lane];
    int s = row_start[n], e = row_start[n + 1];
    int i = s;
    for (; i + 1 < e; i += 2) {
        int c0 = col[i], c1 = col[i + 1];
        z += hin[(long)c0 * 64 + lane] + hin[(long)c1 * 64 + lane];
    }
    if (i < e) z += hin[(long)col[i] * 64 + lane];
    zsh[wave][lane] = z;
    __syncthreads();

    float acc = b1[lane];
    for (int k = 0; k < 64; k++) acc += zsh[wave][k] * W1[k * 64 + lane];
    acc = fmaxf(acc, 0.f);
    tsh[wave][lane] = acc;
    __syncthreads();

    float acc2 = b2[lane];
    for (int k = 0; k < 64; k++) acc2 += tsh[wave][k] * W2[k * 64 + lane];
    acc2 = fmaxf(acc2, 0.f);
    hout[(long)n * 64 + lane] = acc2;
    __syncthreads();

    tsh[wave][lane] = acc2;
    __syncthreads();
    float jkv = 0.f;
    for (int k = 0; k < 64; k++) jkv += tsh[wave][k] * Wjk_blk[k * 64 + lane];
    jk[(long)n * 64 + lane] += jkv;
}

// ---------------- global add pool (batch is sorted) --------------------------
__global__ void pool_kernel(const float* __restrict__ jk, const int* __restrict__ batch,
                            const float* __restrict__ bjk, float* __restrict__ pooled) {
    const int NPB = 125;                          // 800 * 125 == 100000
    int s = blockIdx.x * NPB, e = s + NPB;
    int lane = threadIdx.x;                       // 64 threads
    float bj = bjk[lane];
    float acc = 0.f;
    int gcur = batch[s];
    for (int n = s; n < e; n++) {
        int g = batch[n];
        if (g != gcur) {
            atomicAdd(pooled + gcur * 64 + lane, acc);
            acc = 0.f; gcur = g;
        }
        acc += jk[(long)n * 64 + lane] + bj;
    }
    atomicAdd(pooled + gcur * 64 + lane, acc);
}

// ---------------- classifier micro-kernels -----------------------------------
__global__ void cls_z(const float* __restrict__ pooled, const float* __restrict__ Wc1,
                      const float* __restrict__ bc1, float* __restrict__ z) {
    int g = blockIdx.x, j = threadIdx.x;
    float acc = bc1[j];
    for (int k = 0; k < 64; k++) acc += pooled[g * 64 + k] * Wc1[k * 64 + j];
    z[g * 64 + j] = acc;
}

__global__ void cls_bn(const float* __restrict__ z, float* __restrict__ mu,
                       float* __restrict__ rstd) {
    int j = threadIdx.x;
    float s = 0.f, sq = 0.f;
    for (int g = 0; g < NUM_GRAPHS; g++) {
        float v = z[g * 64 + j];
        s += v; sq += v * v;
    }
    float m = s / NUM_GRAPHS;
    mu[j] = m;
    rstd[j] = rsqrtf(sq / NUM_GRAPHS - m * m + BN_EPS);
}

__global__ void cls_out(const float* __restrict__ z, const float* __restrict__ mu,
                        const float* __restrict__ rstd,
                        const float* __restrict__ gamma, const float* __restrict__ beta,
                        const float* __restrict__ Wc2, const float* __restrict__ bc2,
                        float* __restrict__ out) {
    int i = blockIdx.x * 64 + threadIdx.x;        // 20 * 64 == 1280
    int g = i / OUT_CH, o = i % OUT_CH;
    float acc = bc2[o];
    for (int j = 0; j < 64; j++) {
        float v = (z[g * 64 + j] - mu[j]) * rstd[j] * gamma[j] + beta[j];
        v = fmaxf(v, 0.f);
        acc += v * Wc2[j * OUT_CH + o];
    }
    out[i] = acc;
}

// -----------------------------------------------------------------------------
extern "C" void kernel_launch(void* const* d_in, const int* in_sizes, int n_in,
                              void* d_out, int out_size, void* d_ws, size_t ws_size,
                              hipStream_t stream) {
    const float* x     = (const float*)d_in[0];
    const int*   ei    = (const int*)d_in[1];
    const int*   batch = (const int*)d_in[2];
    const float* W1f   = (const float*)d_in[3];
    const float* b1f   = (const float*)d_in[4];
    const float* W2f   = (const float*)d_in[5];
    const float* b2f   = (const float*)d_in[6];
    const float* W1r   = (const float*)d_in[7];
    const float* b1r   = (const float*)d_in[8];
    const float* W2r   = (const float*)d_in[9];
    const float* b2r   = (const float*)d_in[10];
    const float* Wjk   = (const float*)d_in[11];
    const float* bjk   = (const float*)d_in[12];
    const float* Wc1   = (const float*)d_in[13];
    const float* bc1   = (const float*)d_in[14];
    const float* gamma = (const float*)d_in[15];
    const float* beta  = (const float*)d_in[16];
    const float* Wc2   = (const float*)d_in[17];
    const float* bc2   = (const float*)d_in[18];

    const int* src = ei;
    const int* dst = ei + N_EDGES;

    // workspace layout
    float* ws     = (float*)d_ws;
    float* hA     = ws;                                   // 6.4M floats
    float* hB     = hA + (long)N_NODES * HID;             // 6.4M floats
    float* jk     = hB + (long)N_NODES * HID;             // 6.4M floats
    float* zbuf   = jk + (long)N_NODES * HID;             // 8192
    float* mu     = zbuf + NUM_GRAPHS * HID;              // 64
    float* rstd   = mu + HID;                             // 64
    float* pooled = rstd + HID;                           // 8192
    int*   iws       = (int*)(pooled + NUM_GRAPHS * HID);
    int*   row_start = iws;                               // 100001
    int*   cnt       = row_start + N_NODES + 1;           // 100000
    int*   bsum      = cnt + N_NODES;                     // 391(+pad)
    int*   col       = bsum + 512;                        // 1.6M

    // ---- CSR build (rows = dst, cols = src) ----
    zero_i<<<128, 256, 0, stream>>>(cnt, N_NODES);
    hist<<<N_EDGES / 256, 256, 0, stream>>>(dst, cnt);
    scan_local<<<SCAN_NB, 256, 0, stream>>>(cnt, row_start, bsum);
    scan_bsum<<<1, 64, 0, stream>>>(bsum);
    add_off<<<SCAN_NB, 256, 0, stream>>>(row_start, bsum);
    zero_i<<<128, 256, 0, stream>>>(cnt, N_NODES);
    fill_csr<<<N_EDGES / 256, 256, 0, stream>>>(src, dst, row_start, cnt, col);

    zero_f<<<32, 256, 0, stream>>>(pooled, NUM_GRAPHS * HID);

    // ---- layer 0 (fused gather + MLP + JK) ----
    mlp0_fused<<<N_NODES / 4, 256, 0, stream>>>(x, row_start, col,
                                                W1f, b1f, W2f, b2f, Wjk, hA, jk);

    // ---- layers 1..3 ----
    float* hin = hA; float* hout = hB;
    for (int l = 1; l < N_LAYERS; l++) {
        mlp64_fused<<<N_NODES / 4, 256, 0, stream>>>(
            hin, row_start, col,
            W1r + (long)(l - 1) * HID * HID, b1r + (long)(l - 1) * HID,
            W2r + (long)(l - 1) * HID * HID, b2r + (long)(l - 1) * HID,
            Wjk + (long)l * HID * HID, hout, jk);
        float* tmp = hin; hin = hout; hout = tmp;
    }

    // ---- JK bias + global add pool ----
    pool_kernel<<<N_NODES / 125, 64, 0, stream>>>(jk, batch, bjk, pooled);

    // ---- classifier ----
    cls_z<<<NUM_GRAPHS, 64, 0, stream>>>(pooled, Wc1, bc1, zbuf);
    cls_bn<<<1, 64, 0, stream>>>(zbuf, mu, rstd);
    cls_out<<<(NUM_GRAPHS * OUT_CH) / 64, 64, 0, stream>>>(
        zbuf, mu, rstd, gamma, beta, Wc2, bc2, (float*)d_out);
}

// Round 6
// 1157.475 us; speedup vs baseline: 2.1382x; 1.1339x over previous
//
#include <hip/hip_runtime.h>
#include <hip/hip_bf16.h>

#define N_NODES    100000
#define N_EDGES    1600000
#define IN_CH      128
#define HID        64
#define N_LAYERS   4
#define OUT_CH     10
#define NUM_GRAPHS 128
#define BN_EPS     1e-5f
#define SCAN_NB    391            // ceil(100000/256)

typedef __hip_bfloat16 bf16;

// ---------------- utility zeroing (no hipMemsetAsync under graph capture) ----
__global__ void zero_i(int* __restrict__ p, int n) {
    int i = blockIdx.x * 256 + threadIdx.x;
    int st = gridDim.x * 256;
    for (; i < n; i += st) p[i] = 0;
}
__global__ void zero_f(float* __restrict__ p, int n) {
    int i = blockIdx.x * 256 + threadIdx.x;
    int st = gridDim.x * 256;
    for (; i < n; i += st) p[i] = 0.f;
}

// ---------------- CSR build: rows = dst, cols = src --------------------------
__global__ void hist(const int* __restrict__ dst, int* __restrict__ cnt) {
    int e = blockIdx.x * 256 + threadIdx.x;       // 6250 * 256 == 1.6M exact
    atomicAdd(&cnt[dst[e]], 1);
}

__global__ void scan_local(const int* __restrict__ cnt, int* __restrict__ row_start,
                           int* __restrict__ bsum) {
    __shared__ int sh[256];
    int t = threadIdx.x, i = blockIdx.x * 256 + t;
    int v = (i < N_NODES) ? cnt[i] : 0;
    sh[t] = v;
    __syncthreads();
    for (int off = 1; off < 256; off <<= 1) {
        int add = (t >= off) ? sh[t - off] : 0;
        __syncthreads();
        sh[t] += add;
        __syncthreads();
    }
    if (i < N_NODES) row_start[i] = sh[t] - v;    // exclusive
    if (t == 255) bsum[blockIdx.x] = sh[255];
}

__global__ void scan_bsum(int* __restrict__ bsum) {
    if (threadIdx.x == 0) {
        int acc = 0;
        for (int b = 0; b < SCAN_NB; b++) { int v = bsum[b]; bsum[b] = acc; acc += v; }
    }
}

__global__ void add_off(int* __restrict__ row_start, const int* __restrict__ bsum) {
    int i = blockIdx.x * 256 + threadIdx.x;
    if (i < N_NODES) row_start[i] += bsum[blockIdx.x];
    if (i == 0) row_start[N_NODES] = N_EDGES;
}

__global__ void fill_csr(const int* __restrict__ src, const int* __restrict__ dst,
                         const int* __restrict__ row_start, int* __restrict__ cur,
                         int* __restrict__ col) {
    int e = blockIdx.x * 256 + threadIdx.x;       // 6250 * 256
    int d = dst[e];
    int slot = row_start[d] + atomicAdd(&cur[d], 1);
    col[slot] = src[e];
}

// ---------------- layer-0 pre-projection: y0 = x @ W1f (NO bias) -------------
// Exact restructure: (z)@W1 = y[self] + sum_nb y[nb]; bias added post-gather.
__global__ void proj0(const float* __restrict__ x, const float* __restrict__ W1,
                      float* __restrict__ y, bf16* __restrict__ ybf) {
    __shared__ float xsh[4][IN_CH];
    const int wave = threadIdx.x >> 6, lane = threadIdx.x & 63;
    const int n = blockIdx.x * 4 + wave;          // 25000 * 4 == 100000
    xsh[wave][lane]      = x[(long)n * IN_CH + lane];
    xsh[wave][64 + lane] = x[(long)n * IN_CH + 64 + lane];
    // per-wave LDS only: no barrier needed (wave64 lockstep + compiler waitcnt)
    float acc = 0.f;
    for (int k = 0; k < IN_CH; k += 4) {
        float4 xv = *(const float4*)&xsh[wave][k];
        acc += xv.x * W1[(k + 0) * 64 + lane];
        acc += xv.y * W1[(k + 1) * 64 + lane];
        acc += xv.z * W1[(k + 2) * 64 + lane];
        acc += xv.w * W1[(k + 3) * 64 + lane];
    }
    y[(long)n * 64 + lane]   = acc;
    ybf[(long)n * 64 + lane] = __float2bfloat16(acc);
}

// ---------------- fused layer: gather(y) -> relu -> W2 -> JK (+ next W1) -----
// t   = relu( y[n] + sum_nb bf16(y[nb]) + b1 )
// h   = relu( t @ W2 + b2 )
// jk (+)= h @ Wjk_blk
// if HAS_NEXT: ynext = h @ W1next  (fp32 + bf16 copies)
template <bool FIRST, bool HAS_NEXT>
__global__ void layer_fused(const float* __restrict__ yself, const bf16* __restrict__ ybf,
                            const int* __restrict__ row_start, const int* __restrict__ col,
                            const float* __restrict__ b1, const float* __restrict__ W2,
                            const float* __restrict__ b2, const float* __restrict__ Wjk_blk,
                            const float* __restrict__ W1n,
                            float* __restrict__ ynext, bf16* __restrict__ ynext_bf,
                            float* __restrict__ jk) {
    __shared__ float tsh[4][64];
    __shared__ float hsh[4][64];
    const int wave = threadIdx.x >> 6, lane = threadIdx.x & 63;
    const int n = blockIdx.x * 4 + wave;

    // gather (x4 unrolled for MLR; col/row_start are wave-uniform -> scalar loads)
    float t = yself[(long)n * 64 + lane] + b1[lane];
    int s = row_start[n], e = row_start[n + 1];
    int i = s;
    for (; i + 3 < e; i += 4) {
        int c0 = col[i], c1 = col[i + 1], c2 = col[i + 2], c3 = col[i + 3];
        float a = __bfloat162float(ybf[(long)c0 * 64 + lane]);
        float b = __bfloat162float(ybf[(long)c1 * 64 + lane]);
        float c = __bfloat162float(ybf[(long)c2 * 64 + lane]);
        float d = __bfloat162float(ybf[(long)c3 * 64 + lane]);
        t += (a + b) + (c + d);
    }
    for (; i < e; i++) t += __bfloat162float(ybf[(long)col[i] * 64 + lane]);
    t = fmaxf(t, 0.f);
    tsh[wave][lane] = t;          // per-wave slice: no __syncthreads anywhere

    float h = b2[lane];
    for (int k = 0; k < 64; k += 4) {
        float4 tv = *(const float4*)&tsh[wave][k];
        h += tv.x * W2[(k + 0) * 64 + lane];
        h += tv.y * W2[(k + 1) * 64 + lane];
        h += tv.z * W2[(k + 2) * 64 + lane];
        h += tv.w * W2[(k + 3) * 64 + lane];
    }
    h = fmaxf(h, 0.f);
    hsh[wave][lane] = h;

    float j = 0.f, yn = 0.f;
    for (int k = 0; k < 64; k += 4) {
        float4 hv = *(const float4*)&hsh[wave][k];
        j += hv.x * Wjk_blk[(k + 0) * 64 + lane];
        j += hv.y * Wjk_blk[(k + 1) * 64 + lane];
        j += hv.z * Wjk_blk[(k + 2) * 64 + lane];
        j += hv.w * Wjk_blk[(k + 3) * 64 + lane];
        if (HAS_NEXT) {
            yn += hv.x * W1n[(k + 0) * 64 + lane];
            yn += hv.y * W1n[(k + 1) * 64 + lane];
            yn += hv.z * W1n[(k + 2) * 64 + lane];
            yn += hv.w * W1n[(k + 3) * 64 + lane];
        }
    }
    long idx = (long)n * 64 + lane;
    jk[idx] = FIRST ? j : (jk[idx] + j);
    if (HAS_NEXT) {
        ynext[idx]    = yn;
        ynext_bf[idx] = __float2bfloat16(yn);
    }
}

// ---------------- global add pool (batch is sorted) --------------------------
__global__ void pool_kernel(const float* __restrict__ jk, const int* __restrict__ batch,
                            const float* __restrict__ bjk, float* __restrict__ pooled) {
    const int NPB = 125;                          // 800 * 125 == 100000
    int s = blockIdx.x * NPB, e = s + NPB;
    int lane = threadIdx.x;                       // 64 threads
    float bj = bjk[lane];
    float acc = 0.f;
    int gcur = batch[s];
    for (int n = s; n < e; n++) {
        int g = batch[n];
        if (g != gcur) {
            atomicAdd(pooled + gcur * 64 + lane, acc);
            acc = 0.f; gcur = g;
        }
        acc += jk[(long)n * 64 + lane] + bj;
    }
    atomicAdd(pooled + gcur * 64 + lane, acc);
}

// ---------------- classifier micro-kernels -----------------------------------
__global__ void cls_z(const float* __restrict__ pooled, const float* __restrict__ Wc1,
                      const float* __restrict__ bc1, float* __restrict__ z) {
    int g = blockIdx.x, j = threadIdx.x;
    float acc = bc1[j];
    for (int k = 0; k < 64; k++) acc += pooled[g * 64 + k] * Wc1[k * 64 + j];
    z[g * 64 + j] = acc;
}

__global__ void cls_bn(const float* __restrict__ z, float* __restrict__ mu,
                       float* __restrict__ rstd) {
    int j = threadIdx.x;
    float s = 0.f, sq = 0.f;
    for (int g = 0; g < NUM_GRAPHS; g++) {
        float v = z[g * 64 + j];
        s += v; sq += v * v;
    }
    float m = s / NUM_GRAPHS;
    mu[j] = m;
    rstd[j] = rsqrtf(sq / NUM_GRAPHS - m * m + BN_EPS);
}

__global__ void cls_out(const float* __restrict__ z, const float* __restrict__ mu,
                        const float* __restrict__ rstd,
                        const float* __restrict__ gamma, const float* __restrict__ beta,
                        const float* __restrict__ Wc2, const float* __restrict__ bc2,
                        float* __restrict__ out) {
    int i = blockIdx.x * 64 + threadIdx.x;        // 20 * 64 == 1280
    int g = i / OUT_CH, o = i % OUT_CH;
    float acc = bc2[o];
    for (int j = 0; j < 64; j++) {
        float v = (z[g * 64 + j] - mu[j]) * rstd[j] * gamma[j] + beta[j];
        v = fmaxf(v, 0.f);
        acc += v * Wc2[j * OUT_CH + o];
    }
    out[i] = acc;
}

// -----------------------------------------------------------------------------
extern "C" void kernel_launch(void* const* d_in, const int* in_sizes, int n_in,
                              void* d_out, int out_size, void* d_ws, size_t ws_size,
                              hipStream_t stream) {
    const float* x     = (const float*)d_in[0];
    const int*   ei    = (const int*)d_in[1];
    const int*   batch = (const int*)d_in[2];
    const float* W1f   = (const float*)d_in[3];
    const float* b1f   = (const float*)d_in[4];
    const float* W2f   = (const float*)d_in[5];
    const float* b2f   = (const float*)d_in[6];
    const float* W1r   = (const float*)d_in[7];
    const float* b1r   = (const float*)d_in[8];
    const float* W2r   = (const float*)d_in[9];
    const float* b2r   = (const float*)d_in[10];
    const float* Wjk   = (const float*)d_in[11];
    const float* bjk   = (const float*)d_in[12];
    const float* Wc1   = (const float*)d_in[13];
    const float* bc1   = (const float*)d_in[14];
    const float* gamma = (const float*)d_in[15];
    const float* beta  = (const float*)d_in[16];
    const float* Wc2   = (const float*)d_in[17];
    const float* bc2   = (const float*)d_in[18];

    const int* src = ei;
    const int* dst = ei + N_EDGES;

    // workspace layout
    float* ws     = (float*)d_ws;
    float* yA     = ws;                                   // 6.4M floats
    float* yB     = yA + (long)N_NODES * HID;             // 6.4M floats
    float* jk     = yB + (long)N_NODES * HID;             // 6.4M floats
    float* zbuf   = jk + (long)N_NODES * HID;             // 8192
    float* mu     = zbuf + NUM_GRAPHS * HID;              // 64
    float* rstd   = mu + HID;                             // 64
    float* pooled = rstd + HID;                           // 8192
    bf16*  ybfA   = (bf16*)(pooled + NUM_GRAPHS * HID);   // 6.4M bf16
    bf16*  ybfB   = ybfA + (long)N_NODES * HID;           // 6.4M bf16
    int*   iws       = (int*)(ybfB + (long)N_NODES * HID);
    int*   row_start = iws;                               // 100001
    int*   cnt       = row_start + N_NODES + 1;           // 100000
    int*   bsum      = cnt + N_NODES;                     // 391(+pad)
    int*   col       = bsum + 512;                        // 1.6M

    // ---- CSR build (rows = dst, cols = src) ----
    zero_i<<<128, 256, 0, stream>>>(cnt, N_NODES);
    hist<<<N_EDGES / 256, 256, 0, stream>>>(dst, cnt);
    scan_local<<<SCAN_NB, 256, 0, stream>>>(cnt, row_start, bsum);
    scan_bsum<<<1, 64, 0, stream>>>(bsum);
    add_off<<<SCAN_NB, 256, 0, stream>>>(row_start, bsum);
    zero_i<<<128, 256, 0, stream>>>(cnt, N_NODES);
    fill_csr<<<N_EDGES / 256, 256, 0, stream>>>(src, dst, row_start, cnt, col);

    zero_f<<<32, 256, 0, stream>>>(pooled, NUM_GRAPHS * HID);

    // ---- layer-0 pre-projection (dense, streaming) ----
    proj0<<<N_NODES / 4, 256, 0, stream>>>(x, W1f, yA, ybfA);

    // ---- 4 fused layers ----
    const int NB = N_NODES / 4;
    // layer 0: yA -> (W2f) -> jk block0, next y via W1r[0]
    layer_fused<true, true><<<NB, 256, 0, stream>>>(
        yA, ybfA, row_start, col, b1f, W2f, b2f, Wjk,
        W1r, yB, ybfB, jk);
    // layer 1
    layer_fused<false, true><<<NB, 256, 0, stream>>>(
        yB, ybfB, row_start, col, b1r, W2r, b2r, Wjk + (long)1 * HID * HID,
        W1r + (long)1 * HID * HID, yA, ybfA, jk);
    // layer 2
    layer_fused<false, true><<<NB, 256, 0, stream>>>(
        yA, ybfA, row_start, col, b1r + HID, W2r + (long)1 * HID * HID, b2r + HID,
        Wjk + (long)2 * HID * HID, W1r + (long)2 * HID * HID, yB, ybfB, jk);
    // layer 3 (no next projection)
    layer_fused<false, false><<<NB, 256, 0, stream>>>(
        yB, ybfB, row_start, col, b1r + 2 * HID, W2r + (long)2 * HID * HID,
        b2r + 2 * HID, Wjk + (long)3 * HID * HID, nullptr, nullptr, nullptr, jk);

    // ---- JK bias + global add pool ----
    pool_kernel<<<N_NODES / 125, 64, 0, stream>>>(jk, batch, bjk, pooled);

    // ---- classifier ----
    cls_z<<<NUM_GRAPHS, 64, 0, stream>>>(pooled, Wc1, bc1, zbuf);
    cls_bn<<<1, 64, 0, stream>>>(zbuf, mu, rstd);
    cls_out<<<(NUM_GRAPHS * OUT_CH) / 64, 64, 0, stream>>>(
        zbuf, mu, rstd, gamma, beta, Wc2, bc2, (float*)d_out);
}

// Round 7
// 1021.575 us; speedup vs baseline: 2.4226x; 1.1330x over previous
//
#include <hip/hip_runtime.h>
#include <hip/hip_bf16.h>

#define N_NODES    100000
#define N_EDGES    1600000
#define IN_CH      128
#define HID        64
#define N_LAYERS   4
#define OUT_CH     10
#define NUM_GRAPHS 128
#define BN_EPS     1e-5f
#define SCAN_NB    391            // ceil(100000/256)

typedef __hip_bfloat16 bf16;
__device__ __forceinline__ float bf2f(bf16 v) { return __bfloat162float(v); }

// ---------------- utility zeroing (no hipMemsetAsync under graph capture) ----
__global__ void zero_i(int* __restrict__ p, int n) {
    int i = blockIdx.x * 256 + threadIdx.x;
    int st = gridDim.x * 256;
    for (; i < n; i += st) p[i] = 0;
}
__global__ void zero_f(float* __restrict__ p, int n) {
    int i = blockIdx.x * 256 + threadIdx.x;
    int st = gridDim.x * 256;
    for (; i < n; i += st) p[i] = 0.f;
}

// ---------------- CSR build: rows = dst, cols = src --------------------------
__global__ void hist(const int* __restrict__ dst, int* __restrict__ cnt) {
    int e = blockIdx.x * 256 + threadIdx.x;       // 6250 * 256 == 1.6M exact
    atomicAdd(&cnt[dst[e]], 1);
}

__global__ void scan_local(const int* __restrict__ cnt, int* __restrict__ row_start,
                           int* __restrict__ bsum) {
    __shared__ int sh[256];
    int t = threadIdx.x, i = blockIdx.x * 256 + t;
    int v = (i < N_NODES) ? cnt[i] : 0;
    sh[t] = v;
    __syncthreads();
    for (int off = 1; off < 256; off <<= 1) {
        int add = (t >= off) ? sh[t - off] : 0;
        __syncthreads();
        sh[t] += add;
        __syncthreads();
    }
    if (i < N_NODES) row_start[i] = sh[t] - v;    // exclusive
    if (t == 255) bsum[blockIdx.x] = sh[255];
}

// parallel exclusive scan of the 391 chunk totals (1 block, 512 threads)
__global__ void scan_bsum(int* __restrict__ bsum) {
    __shared__ int sh[512];
    int t = threadIdx.x;
    int v = (t < SCAN_NB) ? bsum[t] : 0;
    sh[t] = v;
    __syncthreads();
    for (int off = 1; off < 512; off <<= 1) {
        int add = (t >= off) ? sh[t - off] : 0;
        __syncthreads();
        sh[t] += add;
        __syncthreads();
    }
    if (t < SCAN_NB) bsum[t] = sh[t] - v;         // exclusive
}

__global__ void add_off(int* __restrict__ row_start, const int* __restrict__ bsum) {
    int i = blockIdx.x * 256 + threadIdx.x;
    if (i < N_NODES) row_start[i] += bsum[blockIdx.x];
    if (i == 0) row_start[N_NODES] = N_EDGES;
}

__global__ void fill_csr(const int* __restrict__ src, const int* __restrict__ dst,
                         const int* __restrict__ row_start, int* __restrict__ cur,
                         int* __restrict__ col) {
    int e = blockIdx.x * 256 + threadIdx.x;       // 6250 * 256
    int d = dst[e];
    int slot = row_start[d] + atomicAdd(&cur[d], 1);
    col[slot] = src[e];
}

// ---------------- layer-0 pre-projection: y0 = bf16(x @ W1f) (no bias) -------
__global__ void proj0(const float* __restrict__ x, const float* __restrict__ W1,
                      bf16* __restrict__ ybf) {
    __shared__ float xsh[4][IN_CH];
    const int wave = threadIdx.x >> 6, lane = threadIdx.x & 63;
    const int n = blockIdx.x * 4 + wave;          // 25000 * 4 == 100000
    float2 xv2 = ((const float2*)(x + (long)n * IN_CH))[lane];
    xsh[wave][2 * lane]     = xv2.x;              // stride-2 write: 2-way, free
    xsh[wave][2 * lane + 1] = xv2.y;
    // per-wave LDS slice: no barrier needed (wave-lockstep + compiler waitcnt)
    float acc = 0.f;
    for (int k = 0; k < IN_CH; k += 4) {
        float4 xv = *(const float4*)&xsh[wave][k];
        acc += xv.x * W1[(k + 0) * 64 + lane];
        acc += xv.y * W1[(k + 1) * 64 + lane];
        acc += xv.z * W1[(k + 2) * 64 + lane];
        acc += xv.w * W1[(k + 3) * 64 + lane];
    }
    ybf[(long)n * 64 + lane] = __float2bfloat16(acc);
}

// ---------------- fused layer: gather(ybf) -> relu -> W2 -> JK (+ next W1) ---
// t = relu( ybf[n] + sum_nb ybf[nb] + b1 );  h = relu(t@W2 + b2)
// jk (+)= h @ Wjk_blk;  if HAS_NEXT: ynext_bf = bf16(h @ W1n)
template <bool FIRST, bool HAS_NEXT>
__global__ void layer_fused(const bf16* __restrict__ ybf,
                            const int* __restrict__ row_start, const int* __restrict__ col,
                            const float* __restrict__ b1, const float* __restrict__ W2,
                            const float* __restrict__ b2, const float* __restrict__ Wjk_blk,
                            const float* __restrict__ W1n,
                            bf16* __restrict__ ynext_bf, float* __restrict__ jk) {
    __shared__ float tsh[4][64];
    __shared__ float hsh[4][64];
    const int wave = threadIdx.x >> 6, lane = threadIdx.x & 63;
    const int n = __builtin_amdgcn_readfirstlane(blockIdx.x * 4 + wave);

    const int s = __builtin_amdgcn_readfirstlane(row_start[n]);
    const int e = __builtin_amdgcn_readfirstlane(row_start[n + 1]);

    float t = bf2f(ybf[(long)n * 64 + lane]) + b1[lane];

    // 16-deep batches: 16 outstanding loads per wave before any accumulation
    int i = s;
    for (; i + 16 <= e; i += 16) {
        float f[16];
        #pragma unroll
        for (int u = 0; u < 16; u++) {
            int c = __builtin_amdgcn_readfirstlane(col[i + u]);
            f[u] = bf2f(ybf[(long)c * 64 + lane]);
        }
        #pragma unroll
        for (int u = 0; u < 16; u++) t += f[u];
    }
    for (; i + 4 <= e; i += 4) {
        float f[4];
        #pragma unroll
        for (int u = 0; u < 4; u++) {
            int c = __builtin_amdgcn_readfirstlane(col[i + u]);
            f[u] = bf2f(ybf[(long)c * 64 + lane]);
        }
        t += (f[0] + f[1]) + (f[2] + f[3]);
    }
    for (; i < e; i++) {
        int c = __builtin_amdgcn_readfirstlane(col[i]);
        t += bf2f(ybf[(long)c * 64 + lane]);
    }
    t = fmaxf(t, 0.f);
    tsh[wave][lane] = t;          // per-wave slice: no __syncthreads anywhere

    float h = b2[lane];
    for (int k = 0; k < 64; k += 4) {
        float4 tv = *(const float4*)&tsh[wave][k];
        h += tv.x * W2[(k + 0) * 64 + lane];
        h += tv.y * W2[(k + 1) * 64 + lane];
        h += tv.z * W2[(k + 2) * 64 + lane];
        h += tv.w * W2[(k + 3) * 64 + lane];
    }
    h = fmaxf(h, 0.f);
    hsh[wave][lane] = h;

    float j = 0.f, yn = 0.f;
    for (int k = 0; k < 64; k += 4) {
        float4 hv = *(const float4*)&hsh[wave][k];
        j += hv.x * Wjk_blk[(k + 0) * 64 + lane];
        j += hv.y * Wjk_blk[(k + 1) * 64 + lane];
        j += hv.z * Wjk_blk[(k + 2) * 64 + lane];
        j += hv.w * Wjk_blk[(k + 3) * 64 + lane];
        if (HAS_NEXT) {
            yn += hv.x * W1n[(k + 0) * 64 + lane];
            yn += hv.y * W1n[(k + 1) * 64 + lane];
            yn += hv.z * W1n[(k + 2) * 64 + lane];
            yn += hv.w * W1n[(k + 3) * 64 + lane];
        }
    }
    long idx = (long)n * 64 + lane;
    jk[idx] = FIRST ? j : (jk[idx] + j);
    if (HAS_NEXT) ynext_bf[idx] = __float2bfloat16(yn);
}

// ---------------- global add pool (batch is sorted) --------------------------
__global__ void pool_kernel(const float* __restrict__ jk, const int* __restrict__ batch,
                            const float* __restrict__ bjk, float* __restrict__ pooled) {
    const int NPB = 125;                          // 800 * 125 == 100000
    int s = blockIdx.x * NPB, e = s + NPB;
    int lane = threadIdx.x;                       // 64 threads
    float bj = bjk[lane];
    float acc = 0.f;
    int gcur = batch[s];
    for (int n = s; n < e; n++) {
        int g = batch[n];
        if (g != gcur) {
            atomicAdd(pooled + gcur * 64 + lane, acc);
            acc = 0.f; gcur = g;
        }
        acc += jk[(long)n * 64 + lane] + bj;
    }
    atomicAdd(pooled + gcur * 64 + lane, acc);
}

// ---------------- classifier micro-kernels -----------------------------------
__global__ void cls_z(const float* __restrict__ pooled, const float* __restrict__ Wc1,
                      const float* __restrict__ bc1, float* __restrict__ z) {
    int g = blockIdx.x, j = threadIdx.x;
    float acc = bc1[j];
    for (int k = 0; k < 64; k++) acc += pooled[g * 64 + k] * Wc1[k * 64 + j];
    z[g * 64 + j] = acc;
}

__global__ void cls_bn(const float* __restrict__ z, float* __restrict__ mu,
                       float* __restrict__ rstd) {
    int j = threadIdx.x;
    float s = 0.f, sq = 0.f;
    for (int g = 0; g < NUM_GRAPHS; g++) {
        float v = z[g * 64 + j];
        s += v; sq += v * v;
    }
    float m = s / NUM_GRAPHS;
    mu[j] = m;
    rstd[j] = rsqrtf(sq / NUM_GRAPHS - m * m + BN_EPS);
}

__global__ void cls_out(const float* __restrict__ z, const float* __restrict__ mu,
                        const float* __restrict__ rstd,
                        const float* __restrict__ gamma, const float* __restrict__ beta,
                        const float* __restrict__ Wc2, const float* __restrict__ bc2,
                        float* __restrict__ out) {
    int i = blockIdx.x * 64 + threadIdx.x;        // 20 * 64 == 1280
    int g = i / OUT_CH, o = i % OUT_CH;
    float acc = bc2[o];
    for (int j = 0; j < 64; j++) {
        float v = (z[g * 64 + j] - mu[j]) * rstd[j] * gamma[j] + beta[j];
        v = fmaxf(v, 0.f);
        acc += v * Wc2[j * OUT_CH + o];
    }
    out[i] = acc;
}

// -----------------------------------------------------------------------------
extern "C" void kernel_launch(void* const* d_in, const int* in_sizes, int n_in,
                              void* d_out, int out_size, void* d_ws, size_t ws_size,
                              hipStream_t stream) {
    const float* x     = (const float*)d_in[0];
    const int*   ei    = (const int*)d_in[1];
    const int*   batch = (const int*)d_in[2];
    const float* W1f   = (const float*)d_in[3];
    const float* b1f   = (const float*)d_in[4];
    const float* W2f   = (const float*)d_in[5];
    const float* b2f   = (const float*)d_in[6];
    const float* W1r   = (const float*)d_in[7];
    const float* b1r   = (const float*)d_in[8];
    const float* W2r   = (const float*)d_in[9];
    const float* b2r   = (const float*)d_in[10];
    const float* Wjk   = (const float*)d_in[11];
    const float* bjk   = (const float*)d_in[12];
    const float* Wc1   = (const float*)d_in[13];
    const float* bc1   = (const float*)d_in[14];
    const float* gamma = (const float*)d_in[15];
    const float* beta  = (const float*)d_in[16];
    const float* Wc2   = (const float*)d_in[17];
    const float* bc2   = (const float*)d_in[18];

    const int* src = ei;
    const int* dst = ei + N_EDGES;

    // workspace layout
    float* ws     = (float*)d_ws;
    float* jk     = ws;                                   // 6.4M floats
    float* zbuf   = jk + (long)N_NODES * HID;             // 8192
    float* mu     = zbuf + NUM_GRAPHS * HID;              // 64
    float* rstd   = mu + HID;                             // 64
    float* pooled = rstd + HID;                           // 8192
    bf16*  ybfA   = (bf16*)(pooled + NUM_GRAPHS * HID);   // 6.4M bf16
    bf16*  ybfB   = ybfA + (long)N_NODES * HID;           // 6.4M bf16
    int*   iws       = (int*)(ybfB + (long)N_NODES * HID);
    int*   row_start = iws;                               // 100001
    int*   cnt       = row_start + N_NODES + 8;           // 100000 (cnt+cur adjacent)
    int*   cur       = cnt + N_NODES;                     // 100000
    int*   bsum      = cur + N_NODES;                     // 391(+pad)
    int*   col       = bsum + 512;                        // 1.6M

    // ---- CSR build (rows = dst, cols = src) ----
    zero_i<<<256, 256, 0, stream>>>(cnt, 2 * N_NODES);    // cnt + cur in one pass
    hist<<<N_EDGES / 256, 256, 0, stream>>>(dst, cnt);
    scan_local<<<SCAN_NB, 256, 0, stream>>>(cnt, row_start, bsum);
    scan_bsum<<<1, 512, 0, stream>>>(bsum);
    add_off<<<SCAN_NB, 256, 0, stream>>>(row_start, bsum);
    fill_csr<<<N_EDGES / 256, 256, 0, stream>>>(src, dst, row_start, cur, col);

    zero_f<<<32, 256, 0, stream>>>(pooled, NUM_GRAPHS * HID);

    // ---- layer-0 pre-projection (dense, streaming) ----
    proj0<<<N_NODES / 4, 256, 0, stream>>>(x, W1f, ybfA);

    // ---- 4 fused layers ----
    const int NB = N_NODES / 4;
    layer_fused<true, true><<<NB, 256, 0, stream>>>(
        ybfA, row_start, col, b1f, W2f, b2f, Wjk,
        W1r, ybfB, jk);
    layer_fused<false, true><<<NB, 256, 0, stream>>>(
        ybfB, row_start, col, b1r, W2r, b2r, Wjk + (long)1 * HID * HID,
        W1r + (long)1 * HID * HID, ybfA, jk);
    layer_fused<false, true><<<NB, 256, 0, stream>>>(
        ybfA, row_start, col, b1r + HID, W2r + (long)1 * HID * HID, b2r + HID,
        Wjk + (long)2 * HID * HID, W1r + (long)2 * HID * HID, ybfB, jk);
    layer_fused<false, false><<<NB, 256, 0, stream>>>(
        ybfB, row_start, col, b1r + 2 * HID, W2r + (long)2 * HID * HID,
        b2r + 2 * HID, Wjk + (long)3 * HID * HID, nullptr, nullptr, jk);

    // ---- JK bias + global add pool ----
    pool_kernel<<<N_NODES / 125, 64, 0, stream>>>(jk, batch, bjk, pooled);

    // ---- classifier ----
    cls_z<<<NUM_GRAPHS, 64, 0, stream>>>(pooled, Wc1, bc1, zbuf);
    cls_bn<<<1, 64, 0, stream>>>(zbuf, mu, rstd);
    cls_out<<<(NUM_GRAPHS * OUT_CH) / 64, 64, 0, stream>>>(
        zbuf, mu, rstd, gamma, beta, Wc2, bc2, (float*)d_out);
}